// Round 1
// baseline (3011.218 us; speedup 1.0000x reference)
//
#include <hip/hip_runtime.h>
#include <stdint.h>

// ---------------------------------------------------------------------------
// GNN layer, MI355X (gfx950). All GEMMs via v_mfma_f32_32x32x16_f16, fp32 acc.
// Transposed formulation: C^T[out][edge] = W^T[out][k] @ feats^T[k][edge].
// Each wave owns 32 edges (cols) x full output width (8 or 4 32-row m-frags).
// Inter-layer activation handoff stays in registers via cvt_pkrtz +
// v_permlane32_swap_b32 (no LDS round-trip for activations).
// ---------------------------------------------------------------------------

typedef _Float16 h16;
typedef _Float16 half8  __attribute__((ext_vector_type(8)));
typedef float    f32x16 __attribute__((ext_vector_type(16)));
typedef unsigned u32x4  __attribute__((ext_vector_type(4)));

__device__ __forceinline__ f32x16 MFMA(half8 a, half8 b, f32x16 c) {
  return __builtin_amdgcn_mfma_f32_32x32x16_f16(a, b, c, 0, 0, 0);
}

// v_permlane32_swap_b32: new_a = [a_lo | b_lo], new_b = [a_hi | b_hi]
__device__ __forceinline__ void lane_swap(unsigned &a, unsigned &b) {
  asm volatile("v_permlane32_swap_b32 %0, %1" : "+v"(a), "+v"(b));
}

// order-preserving float->uint map (atomicMax-able), init = 0
__device__ __forceinline__ unsigned ordf(float f) {
  unsigned b = __float_as_uint(f);
  return (b & 0x80000000u) ? ~b : (b | 0x80000000u);
}
__device__ __forceinline__ float ordinv(unsigned u) {
  return __uint_as_float((u & 0x80000000u) ? (u ^ 0x80000000u) : ~u);
}

// Stage one weight tile [R=32*MFA rows][32 k] f16 into LDS via global_load_lds.
// LDS layout: row-major 64B rows, 16B chunk index XOR-swizzled with (row>>1)&3
// (pre-swizzled on the GLOBAL source; LDS dest stays linear per G21).
template<int MFA>
__device__ __forceinline__ void stage_tile(h16* dst, const h16* wT, int K, int kt, int tid) {
  int wv = tid >> 6, lane = tid & 63;
#pragma unroll
  for (int it = 0; it < MFA / 2; ++it) {
    int slotbase = it * 256 + wv * 64;       // wave-uniform
    int s = slotbase + lane;
    int row = s >> 2, x = s & 3;
    int c = x ^ ((row >> 1) & 3);
    const h16* src = wT + (size_t)row * K + kt * 32 + c * 8;
    h16* d = dst + slotbase * 8;             // wave-uniform base; lane*16B implicit
    __builtin_amdgcn_global_load_lds((const __attribute__((address_space(1))) unsigned*)src,
                                     (__attribute__((address_space(3))) unsigned*)d, 16, 0, 0);
  }
}

// A-frag read: lane holds W^T[32*mf + (lane&31)][16*ksl + 8*(lane>>5) + i]
__device__ __forceinline__ half8 ldsA(const h16* buf, int mf, int ksl, int lane) {
  int r31 = lane & 31, g = lane >> 5;
  int c = (2 * ksl + g) ^ ((r31 >> 1) & 3);
  return *(const half8*)(buf + mf * 1024 + r31 * 32 + c * 8);
}

// acc(16 f32, D-layout row=(r&3)+8*(r>>2)+4g) + bias [-> relu] -> 8x packed f16
template<bool RELU>
__device__ __forceinline__ void pack_frag(unsigned* hr, const f32x16 a, const float* bias, int g) {
#pragma unroll
  for (int j = 0; j < 8; ++j) {
    int m = 2 * (j & 1) + 8 * (j >> 1) + 4 * g;
    float x = a[2 * j]     + bias[m];
    float y = a[2 * j + 1] + bias[m + 1];
    if (RELU) { x = fmaxf(x, 0.f); y = fmaxf(y, 0.f); }
    auto p = __builtin_amdgcn_cvt_pkrtz(x, y);
    hr[j] = __builtin_bit_cast(unsigned, p);
  }
}

// Build next-GEMM B-frag (k = 16*ks + 8g + i) from packed hregs of this K-tile.
// swap(v_p, u_p) -> (B[p], B[p+2]); ks = 2*kt + ksl, v_p=hr[4ksl+p], u_p=hr[4ksl+2+p]
__device__ __forceinline__ half8 buildB(unsigned* hr, int ksl) {
  unsigned v0 = hr[4 * ksl + 0], v1 = hr[4 * ksl + 1];
  unsigned u0 = hr[4 * ksl + 2], u1 = hr[4 * ksl + 3];
  lane_swap(v0, u0);
  lane_swap(v1, u1);
  u32x4 t = {v0, v1, u0, u1};
  return __builtin_bit_cast(half8, t);
}

// Generic GEMM with B sourced from hregs. GB = global tile counter base (dbuf parity).
template<int MFA, int KT, int GB, int NMFA>
__device__ __forceinline__ void gemm_hregB(f32x16* acc, unsigned (*hreg)[8],
    const h16* wT, int K, const h16* nW, int nK,
    h16 (*wbuf)[8192], int tid, int lane) {
#pragma unroll
  for (int kt = 0; kt < KT; ++kt) {
    __syncthreads();
    if (kt + 1 < KT)  stage_tile<MFA>(wbuf[(GB + kt + 1) & 1], wT, K, kt + 1, tid);
    else if (nW)      stage_tile<NMFA>(wbuf[(GB + kt + 1) & 1], nW, nK, 0, tid);
    const h16* rb = wbuf[(GB + kt) & 1];
#pragma unroll
    for (int ksl = 0; ksl < 2; ++ksl) {
      half8 b = buildB(hreg[kt], ksl);
#pragma unroll
      for (int mf = 0; mf < MFA; ++mf)
        acc[mf] = MFMA(ldsA(rb, mf, ksl, lane), b, acc[mf]);
    }
  }
}

// ---------------------------------------------------------------------------
// Edge kernel: feats(272) -> msg MLP -> msgs(128) -> gate MLP -> gate scalar
// ---------------------------------------------------------------------------
__global__ __launch_bounds__(256, 2) void k_edge(
    const h16* __restrict__ nodes_h, const h16* __restrict__ edges_h,
    const int* __restrict__ senders, const int* __restrict__ receivers,
    const h16* __restrict__ w1t, const h16* __restrict__ w2t, const h16* __restrict__ w3t,
    const h16* __restrict__ a1t, const h16* __restrict__ a2t,
    const float* __restrict__ b1, const float* __restrict__ b2, const float* __restrict__ b3,
    const float* __restrict__ ab1, const float* __restrict__ ab2,
    const float* __restrict__ ag3, const float* __restrict__ ab3,
    h16* __restrict__ msgs_h, float* __restrict__ gate, unsigned* __restrict__ segmax, int E)
{
  __shared__ h16 wbuf[2][8192];   // 2 x 16KB weight tiles
  __shared__ float sb[1025];      // biases + ag_w3

  int tid = threadIdx.x, lane = tid & 63, wv = tid >> 6;
  int g = lane >> 5, c31 = lane & 31;

  sb[tid] = b1[tid];
  sb[256 + tid] = b2[tid];
  if (tid < 128) {
    sb[512 + tid] = b3[tid];
    sb[640 + tid] = ab1[tid];
    sb[768 + tid] = ab2[tid];
    sb[896 + tid] = ag3[tid];
  }
  if (tid == 0) sb[1024] = ab3[0];

  int e = blockIdx.x * 128 + wv * 32 + c31;
  bool ev = (e < E);
  int ec = ev ? e : (E - 1);
  int se = senders[ec], re = receivers[ec];
  const h16* pe = edges_h + (size_t)ec * 16;
  const h16* ps = nodes_h + (size_t)se * 128;
  const h16* pr = nodes_h + (size_t)re * 128;

  stage_tile<8>(wbuf[0], w1t, 288, 0, tid);

  // feats^T B-frag: segment chosen by (uniform, compile-time) ks
  auto loadB1 = [&](int ks) -> half8 {
    if (ks >= 17) { half8 z = {}; return z; }  // K pad 272..287
    const h16* base = (ks == 0) ? pe : (ks < 9) ? (ps + 16 * ks - 16) : (pr + 16 * ks - 144);
    return *(const half8*)(base + 8 * g);
  };

  // ---- GEMM1: h1^T[256][32e] = W1^T @ feats^T, K=288 (9 tiles, global 0..8)
  f32x16 acc1[8];
#pragma unroll
  for (int i = 0; i < 8; ++i) acc1[i] = f32x16{};
  half8 bq0 = loadB1(0), bq1 = loadB1(1);
#pragma unroll
  for (int kt = 0; kt < 9; ++kt) {
    __syncthreads();
    if (kt < 8) stage_tile<8>(wbuf[(kt + 1) & 1], w1t, 288, kt + 1, tid);
    else        stage_tile<8>(wbuf[1], w2t, 256, 0, tid);
    half8 n0 = {}, n1 = {};
    if (kt < 8) { n0 = loadB1(2 * kt + 2); n1 = loadB1(2 * kt + 3); }
    const h16* rb = wbuf[kt & 1];
#pragma unroll
    for (int mf = 0; mf < 8; ++mf) acc1[mf] = MFMA(ldsA(rb, mf, 0, lane), bq0, acc1[mf]);
#pragma unroll
    for (int mf = 0; mf < 8; ++mf) acc1[mf] = MFMA(ldsA(rb, mf, 1, lane), bq1, acc1[mf]);
    bq0 = n0; bq1 = n1;
  }
  unsigned hreg1[8][8];
#pragma unroll
  for (int mf = 0; mf < 8; ++mf) pack_frag<true>(hreg1[mf], acc1[mf], sb + 32 * mf, g);

  // ---- GEMM2: h2^T = W2^T @ h1^T, K=256 (tiles 9..16)
  f32x16 acc2[8];
#pragma unroll
  for (int i = 0; i < 8; ++i) acc2[i] = f32x16{};
  gemm_hregB<8, 8, 9, 4>(acc2, hreg1, w2t, 256, w3t, 256, wbuf, tid, lane);
  unsigned hreg2[8][8];
#pragma unroll
  for (int mf = 0; mf < 8; ++mf) pack_frag<false>(hreg2[mf], acc2[mf], sb + 256 + 32 * mf, g);

  // ---- GEMM3: msgs^T[128][32e] = W3^T @ h2^T, K=256 (tiles 17..24)
  f32x16 acc3[4];
#pragma unroll
  for (int i = 0; i < 4; ++i) acc3[i] = f32x16{};
  gemm_hregB<4, 8, 17, 4>(acc3, hreg2, w3t, 256, a1t, 128, wbuf, tid, lane);
  unsigned hreg3[4][8];
  unsigned* mrow = (unsigned*)(msgs_h + (size_t)ec * 128);
#pragma unroll
  for (int mf = 0; mf < 4; ++mf) {
    pack_frag<false>(hreg3[mf], acc3[mf], sb + 512 + 32 * mf, g);
    if (ev) {
#pragma unroll
      for (int j = 0; j < 8; ++j)
        mrow[16 * mf + (j & 1) + 4 * (j >> 1) + 2 * g] = hreg3[mf][j];
    }
  }

  // ---- GEMM4: g1^T = Ag1^T @ msgs^T, K=128 (tiles 25..28)
  f32x16 acc4[4];
#pragma unroll
  for (int i = 0; i < 4; ++i) acc4[i] = f32x16{};
  gemm_hregB<4, 4, 25, 4>(acc4, hreg3, a1t, 128, a2t, 128, wbuf, tid, lane);
  unsigned hreg4[4][8];
#pragma unroll
  for (int mf = 0; mf < 4; ++mf) pack_frag<true>(hreg4[mf], acc4[mf], sb + 640 + 32 * mf, g);

  // ---- GEMM5: g2^T = Ag2^T @ g1^T, K=128 (tiles 29..32)
  f32x16 acc5[4];
#pragma unroll
  for (int i = 0; i < 4; ++i) acc5[i] = f32x16{};
  gemm_hregB<4, 4, 29, 4>(acc5, hreg4, a2t, 128, (const h16*)nullptr, 0, wbuf, tid, lane);

  // ---- gate[e] = (g2 + ab2) . ag_w3 + ab3
  float gs = 0.f;
#pragma unroll
  for (int mf = 0; mf < 4; ++mf)
#pragma unroll
    for (int r = 0; r < 16; ++r) {
      int m = 32 * mf + (r & 3) + 8 * (r >> 2) + 4 * g;
      gs += (acc5[mf][r] + sb[768 + m]) * sb[896 + m];
    }
  unsigned xa = __float_as_uint(gs), xb = xa;
  lane_swap(xa, xb);  // xa = lo-half gs for all, xb = hi-half gs for all
  float tot = __uint_as_float(xa) + __uint_as_float(xb) + sb[1024];
  if (lane < 32 && ev) {
    gate[e] = tot;
    atomicMax(segmax + re, ordf(tot));
  }
}

// ---------------------------------------------------------------------------
// Update kernel: [nodes | aggr](256) -> update MLP -> out(128) fp32
// ---------------------------------------------------------------------------
__global__ __launch_bounds__(256, 2) void k_update(
    const h16* __restrict__ nodes_h, const h16* __restrict__ aggr_h,
    const h16* __restrict__ u1t, const h16* __restrict__ u2t, const h16* __restrict__ u3t,
    const float* __restrict__ b1, const float* __restrict__ b2, const float* __restrict__ b3,
    float* __restrict__ out, int N)
{
  __shared__ h16 wbuf[2][8192];
  __shared__ float sb[640];
  int tid = threadIdx.x, lane = tid & 63, wv = tid >> 6;
  int g = lane >> 5, c31 = lane & 31;
  sb[tid] = b1[tid];
  sb[256 + tid] = b2[tid];
  if (tid < 128) sb[512 + tid] = b3[tid];

  int n = blockIdx.x * 128 + wv * 32 + c31;
  int nc = (n < N) ? n : (N - 1);
  const h16* pn = nodes_h + (size_t)nc * 128;
  const h16* pa = aggr_h + (size_t)nc * 128;
  auto loadB = [&](int ks) -> half8 {
    const h16* base = (ks < 8) ? (pn + 16 * ks) : (pa + 16 * ks - 128);
    return *(const half8*)(base + 8 * g);
  };

  stage_tile<8>(wbuf[0], u1t, 256, 0, tid);
  f32x16 acc1[8];
#pragma unroll
  for (int i = 0; i < 8; ++i) acc1[i] = f32x16{};
  half8 bq0 = loadB(0), bq1 = loadB(1);
#pragma unroll
  for (int kt = 0; kt < 8; ++kt) {
    __syncthreads();
    if (kt < 7) stage_tile<8>(wbuf[(kt + 1) & 1], u1t, 256, kt + 1, tid);
    else        stage_tile<8>(wbuf[0], u2t, 256, 0, tid);
    half8 n0 = {}, n1 = {};
    if (kt < 7) { n0 = loadB(2 * kt + 2); n1 = loadB(2 * kt + 3); }
    const h16* rb = wbuf[kt & 1];
#pragma unroll
    for (int mf = 0; mf < 8; ++mf) acc1[mf] = MFMA(ldsA(rb, mf, 0, lane), bq0, acc1[mf]);
#pragma unroll
    for (int mf = 0; mf < 8; ++mf) acc1[mf] = MFMA(ldsA(rb, mf, 1, lane), bq1, acc1[mf]);
    bq0 = n0; bq1 = n1;
  }
  unsigned hr1[8][8];
#pragma unroll
  for (int mf = 0; mf < 8; ++mf) pack_frag<true>(hr1[mf], acc1[mf], sb + 32 * mf, g);

  f32x16 acc2[8];
#pragma unroll
  for (int i = 0; i < 8; ++i) acc2[i] = f32x16{};
  gemm_hregB<8, 8, 8, 4>(acc2, hr1, u2t, 256, u3t, 256, wbuf, tid, lane);
  unsigned hr2[8][8];
#pragma unroll
  for (int mf = 0; mf < 8; ++mf) pack_frag<false>(hr2[mf], acc2[mf], sb + 256 + 32 * mf, g);

  f32x16 acc3[4];
#pragma unroll
  for (int i = 0; i < 4; ++i) acc3[i] = f32x16{};
  gemm_hregB<4, 8, 16, 4>(acc3, hr2, u3t, 256, (const h16*)nullptr, 0, wbuf, tid, lane);

  if (n < N) {
    float2* orow = (float2*)(out + (size_t)n * 128);
#pragma unroll
    for (int mf = 0; mf < 4; ++mf)
#pragma unroll
      for (int j = 0; j < 8; ++j) {
        int m = 32 * mf + 2 * (j & 1) + 8 * (j >> 1) + 4 * g;
        float2 v;
        v.x = acc3[mf][2 * j]     + sb[512 + m];
        v.y = acc3[mf][2 * j + 1] + sb[512 + m + 1];
        orow[m >> 1] = v;
      }
  }
}

// ---------------------------------------------------------------------------
// Softmax denom + scatter aggregation + converts
// ---------------------------------------------------------------------------
__global__ void k_denom(const float* __restrict__ gate, const int* __restrict__ recv,
                        const unsigned* __restrict__ segmax, float* __restrict__ denom, int E) {
  int t = blockIdx.x * 256 + threadIdx.x;
  if (t >= E) return;
  int r = recv[t];
  float w = __expf(gate[t] - ordinv(segmax[r]));
  atomicAdd(denom + r, w);
}

__global__ void k_aggr(const float* __restrict__ gate, const int* __restrict__ recv,
                       const unsigned* __restrict__ segmax, const float* __restrict__ denom,
                       const h16* __restrict__ msgs_h, float* __restrict__ aggr, int E) {
  int t = blockIdx.x * 256 + threadIdx.x;
  int e = t >> 2, q = t & 3;
  if (e >= E) return;
  int r = recv[e];
  float attn = __expf(gate[e] - ordinv(segmax[r])) / denom[r];
  typedef _Float16 h2 __attribute__((ext_vector_type(2)));
  const h2* mp = (const h2*)(msgs_h + (size_t)e * 128 + q * 32);
  float* ap = aggr + (size_t)r * 128 + q * 32;
#pragma unroll
  for (int j = 0; j < 16; ++j) {
    h2 h = mp[j];
    atomicAdd(ap + 2 * j,     attn * (float)h[0]);
    atomicAdd(ap + 2 * j + 1, attn * (float)h[1]);
  }
}

__global__ void k_f2h(const float* __restrict__ s, h16* __restrict__ d, long n4) {
  long i = (long)blockIdx.x * 256 + threadIdx.x;
  if (i >= n4) return;
  float4 v = ((const float4*)s)[i];
  union { h16 h[4]; uint2 u; } o;
  o.h[0] = (h16)v.x; o.h[1] = (h16)v.y; o.h[2] = (h16)v.z; o.h[3] = (h16)v.w;
  ((uint2*)d)[i] = o.u;
}

// wt[o][k] = w[k][o] (f16), zero-padded to Kp
__global__ void k_wt(const float* __restrict__ w, h16* __restrict__ wt, int K, int O, int Kp) {
  int t = blockIdx.x * 256 + threadIdx.x;
  if (t >= O * Kp) return;
  int o = t / Kp, k = t - o * Kp;
  wt[t] = (k < K) ? (h16)w[(size_t)k * O + o] : (h16)0.f;
}

// ---------------------------------------------------------------------------
extern "C" void kernel_launch(void* const* d_in, const int* in_sizes, int n_in,
                              void* d_out, int out_size, void* d_ws, size_t ws_size,
                              hipStream_t stream) {
  const float* nodes  = (const float*)d_in[0];
  const float* edges  = (const float*)d_in[1];
  const int* senders  = (const int*)d_in[2];
  const int* receivers= (const int*)d_in[3];
  const float* msg_w1 = (const float*)d_in[4];  const float* msg_b1 = (const float*)d_in[5];
  const float* msg_w2 = (const float*)d_in[6];  const float* msg_b2 = (const float*)d_in[7];
  const float* msg_w3 = (const float*)d_in[8];  const float* msg_b3 = (const float*)d_in[9];
  const float* ag_w1  = (const float*)d_in[10]; const float* ag_b1  = (const float*)d_in[11];
  const float* ag_w2  = (const float*)d_in[12]; const float* ag_b2  = (const float*)d_in[13];
  const float* ag_w3  = (const float*)d_in[14]; const float* ag_b3  = (const float*)d_in[15];
  const float* up_w1  = (const float*)d_in[16]; const float* up_b1  = (const float*)d_in[17];
  const float* up_w2  = (const float*)d_in[18]; const float* up_b2  = (const float*)d_in[19];
  const float* up_w3  = (const float*)d_in[20]; const float* up_b3  = (const float*)d_in[21];

  int N = in_sizes[0] / 128;
  int E = in_sizes[2];
  float* out = (float*)d_out;

  char* ws = (char*)d_ws;
  size_t off = 0;
  auto alloc = [&](size_t bytes) -> char* {
    char* p = ws + off; off += (bytes + 255) & ~(size_t)255; return p;
  };
  h16* nodes_h = (h16*)alloc((size_t)N * 128 * 2);
  h16* edges_h = (h16*)alloc((size_t)E * 16 * 2);
  h16* w1t = (h16*)alloc(256 * 288 * 2);
  h16* w2t = (h16*)alloc(256 * 256 * 2);
  h16* w3t = (h16*)alloc(128 * 256 * 2);
  h16* a1t = (h16*)alloc(128 * 128 * 2);
  h16* a2t = (h16*)alloc(128 * 128 * 2);
  h16* u1t = (h16*)alloc(256 * 256 * 2);
  h16* u2t = (h16*)alloc(256 * 256 * 2);
  h16* u3t = (h16*)alloc(128 * 256 * 2);
  h16* msgs_h = (h16*)alloc((size_t)E * 128 * 2);
  float* gate = (float*)alloc((size_t)E * 4);
  unsigned* segmax = (unsigned*)alloc((size_t)N * 4);
  float* denom = (float*)alloc((size_t)N * 4);
  float* aggr = (float*)alloc((size_t)N * 128 * 4);
  h16* aggr_h = (h16*)alloc((size_t)N * 128 * 2);

  // init (ordered-uint min == 0, so plain zero memsets suffice)
  hipMemsetAsync(segmax, 0, (size_t)N * 4, stream);
  hipMemsetAsync(denom, 0, (size_t)N * 4, stream);
  hipMemsetAsync(aggr, 0, (size_t)N * 128 * 4, stream);

  // converts
  long n4n = (long)N * 128 / 4, n4e = (long)E * 16 / 4;
  k_f2h<<<(n4n + 255) / 256, 256, 0, stream>>>(nodes, nodes_h, n4n);
  k_f2h<<<(n4e + 255) / 256, 256, 0, stream>>>(edges, edges_h, n4e);
  k_wt<<<(256 * 288 + 255) / 256, 256, 0, stream>>>(msg_w1, w1t, 272, 256, 288);
  k_wt<<<(256 * 256 + 255) / 256, 256, 0, stream>>>(msg_w2, w2t, 256, 256, 256);
  k_wt<<<(128 * 256 + 255) / 256, 256, 0, stream>>>(msg_w3, w3t, 256, 128, 256);
  k_wt<<<(128 * 128 + 255) / 256, 256, 0, stream>>>(ag_w1, a1t, 128, 128, 128);
  k_wt<<<(128 * 128 + 255) / 256, 256, 0, stream>>>(ag_w2, a2t, 128, 128, 128);
  k_wt<<<(256 * 256 + 255) / 256, 256, 0, stream>>>(up_w1, u1t, 256, 256, 256);
  k_wt<<<(256 * 256 + 255) / 256, 256, 0, stream>>>(up_w2, u2t, 256, 256, 256);
  k_wt<<<(128 * 256 + 255) / 256, 256, 0, stream>>>(up_w3, u3t, 256, 128, 256);

  // fused edge pipeline (msgs + gate + segmax)
  k_edge<<<(E + 127) / 128, 256, 0, stream>>>(
      nodes_h, edges_h, senders, receivers, w1t, w2t, w3t, a1t, a2t,
      msg_b1, msg_b2, msg_b3, ag_b1, ag_b2, ag_w3, ag_b3,
      msgs_h, gate, segmax, E);

  // segment softmax + aggregation
  k_denom<<<(E + 255) / 256, 256, 0, stream>>>(gate, receivers, segmax, denom, E);
  k_aggr<<<((E * 4) + 255) / 256, 256, 0, stream>>>(gate, receivers, segmax, denom, msgs_h, aggr, E);
  k_f2h<<<(n4n + 255) / 256, 256, 0, stream>>>(aggr, aggr_h, n4n);

  // node update
  k_update<<<(N + 127) / 128, 256, 0, stream>>>(
      nodes_h, aggr_h, u1t, u2t, u3t, up_b1, up_b2, up_b3, out, N);
}

// Round 3
// 605.711 us; speedup vs baseline: 4.9714x; 4.9714x over previous
//
#include <hip/hip_runtime.h>
#include <stdint.h>

// ---------------------------------------------------------------------------
// GNN layer, MI355X (gfx950). All GEMMs via v_mfma_f32_32x32x16_f16, fp32 acc.
// Transposed formulation: C^T[out][edge] = W^T[out][k] @ feats^T[k][edge].
// Each wave owns 32 edges (cols) x full output width (8 or 4 32-row m-frags).
// Inter-layer activation handoff stays in registers via cvt_pkrtz +
// v_permlane32_swap_b32 (no LDS round-trip for activations).
//
// Aggregation (round 3, hybrid): segment max via atomicMax (ordered uint,
// round-1-proven) + denom via k_denom atomicAdd (round-1-proven) + CSR
// gather for the weighted message sum only (replaces the 51.2M scatter
// atomicAdds that cost 2.67 ms in round 1). CSR scan is a single-wave,
// inspection-verifiable kernel (round 2's 1024-thread scan is quarantined).
// ---------------------------------------------------------------------------

typedef _Float16 h16;
typedef _Float16 half8  __attribute__((ext_vector_type(8)));
typedef _Float16 h16x2  __attribute__((ext_vector_type(2)));
typedef float    f32x16 __attribute__((ext_vector_type(16)));
typedef unsigned u32x4  __attribute__((ext_vector_type(4)));

__device__ __forceinline__ f32x16 MFMA(half8 a, half8 b, f32x16 c) {
  return __builtin_amdgcn_mfma_f32_32x32x16_f16(a, b, c, 0, 0, 0);
}

// v_permlane32_swap_b32: new_a = [a_lo | b_lo], new_b = [a_hi | b_hi]
__device__ __forceinline__ void lane_swap(unsigned &a, unsigned &b) {
  asm volatile("v_permlane32_swap_b32 %0, %1" : "+v"(a), "+v"(b));
}

// order-preserving float->uint map (atomicMax-able), init = 0
__device__ __forceinline__ unsigned ordf(float f) {
  unsigned b = __float_as_uint(f);
  return (b & 0x80000000u) ? ~b : (b | 0x80000000u);
}
__device__ __forceinline__ float ordinv(unsigned u) {
  return __uint_as_float((u & 0x80000000u) ? (u ^ 0x80000000u) : ~u);
}

// Stage one weight tile [R=32*MFA rows][32 k] f16 into LDS via global_load_lds.
// LDS layout: row-major 64B rows, 16B chunk index XOR-swizzled with (row>>1)&3
// (pre-swizzled on the GLOBAL source; LDS dest stays linear per G21).
template<int MFA>
__device__ __forceinline__ void stage_tile(h16* dst, const h16* wT, int K, int kt, int tid) {
  int wv = tid >> 6, lane = tid & 63;
#pragma unroll
  for (int it = 0; it < MFA / 2; ++it) {
    int slotbase = it * 256 + wv * 64;       // wave-uniform
    int s = slotbase + lane;
    int row = s >> 2, x = s & 3;
    int c = x ^ ((row >> 1) & 3);
    const h16* src = wT + (size_t)row * K + kt * 32 + c * 8;
    h16* d = dst + slotbase * 8;             // wave-uniform base; lane*16B implicit
    __builtin_amdgcn_global_load_lds((const __attribute__((address_space(1))) unsigned*)src,
                                     (__attribute__((address_space(3))) unsigned*)d, 16, 0, 0);
  }
}

// A-frag read: lane holds W^T[32*mf + (lane&31)][16*ksl + 8*(lane>>5) + i]
__device__ __forceinline__ half8 ldsA(const h16* buf, int mf, int ksl, int lane) {
  int r31 = lane & 31, g = lane >> 5;
  int c = (2 * ksl + g) ^ ((r31 >> 1) & 3);
  return *(const half8*)(buf + mf * 1024 + r31 * 32 + c * 8);
}

// acc(16 f32, D-layout row=(r&3)+8*(r>>2)+4g) + bias [-> relu] -> 8x packed f16
template<bool RELU>
__device__ __forceinline__ void pack_frag(unsigned* hr, const f32x16 a, const float* bias, int g) {
#pragma unroll
  for (int j = 0; j < 8; ++j) {
    int m = 2 * (j & 1) + 8 * (j >> 1) + 4 * g;
    float x = a[2 * j]     + bias[m];
    float y = a[2 * j + 1] + bias[m + 1];
    if (RELU) { x = fmaxf(x, 0.f); y = fmaxf(y, 0.f); }
    auto p = __builtin_amdgcn_cvt_pkrtz(x, y);
    hr[j] = __builtin_bit_cast(unsigned, p);
  }
}

// Build next-GEMM B-frag (k = 16*ks + 8g + i) from packed hregs of this K-tile.
// swap(v_p, u_p) -> (B[p], B[p+2]); ks = 2*kt + ksl, v_p=hr[4ksl+p], u_p=hr[4ksl+2+p]
__device__ __forceinline__ half8 buildB(unsigned* hr, int ksl) {
  unsigned v0 = hr[4 * ksl + 0], v1 = hr[4 * ksl + 1];
  unsigned u0 = hr[4 * ksl + 2], u1 = hr[4 * ksl + 3];
  lane_swap(v0, u0);
  lane_swap(v1, u1);
  u32x4 t = {v0, v1, u0, u1};
  return __builtin_bit_cast(half8, t);
}

// Generic GEMM with B sourced from hregs. GB = global tile counter base (dbuf parity).
template<int MFA, int KT, int GB, int NMFA>
__device__ __forceinline__ void gemm_hregB(f32x16* acc, unsigned (*hreg)[8],
    const h16* wT, int K, const h16* nW, int nK,
    h16 (*wbuf)[8192], int tid, int lane) {
#pragma unroll
  for (int kt = 0; kt < KT; ++kt) {
    __syncthreads();
    if (kt + 1 < KT)  stage_tile<MFA>(wbuf[(GB + kt + 1) & 1], wT, K, kt + 1, tid);
    else if (nW)      stage_tile<NMFA>(wbuf[(GB + kt + 1) & 1], nW, nK, 0, tid);
    const h16* rb = wbuf[(GB + kt) & 1];
#pragma unroll
    for (int ksl = 0; ksl < 2; ++ksl) {
      half8 b = buildB(hreg[kt], ksl);
#pragma unroll
      for (int mf = 0; mf < MFA; ++mf)
        acc[mf] = MFMA(ldsA(rb, mf, ksl, lane), b, acc[mf]);
    }
  }
}

// ---------------------------------------------------------------------------
// Edge kernel: feats(272) -> msg MLP -> msgs(128) -> gate MLP -> gate scalar
// (verbatim round-1 version, incl. atomicMax segmax)
// ---------------------------------------------------------------------------
__global__ __launch_bounds__(256, 2) void k_edge(
    const h16* __restrict__ nodes_h, const h16* __restrict__ edges_h,
    const int* __restrict__ senders, const int* __restrict__ receivers,
    const h16* __restrict__ w1t, const h16* __restrict__ w2t, const h16* __restrict__ w3t,
    const h16* __restrict__ a1t, const h16* __restrict__ a2t,
    const float* __restrict__ b1, const float* __restrict__ b2, const float* __restrict__ b3,
    const float* __restrict__ ab1, const float* __restrict__ ab2,
    const float* __restrict__ ag3, const float* __restrict__ ab3,
    h16* __restrict__ msgs_h, float* __restrict__ gate, unsigned* __restrict__ segmax, int E)
{
  __shared__ h16 wbuf[2][8192];   // 2 x 16KB weight tiles
  __shared__ float sb[1025];      // biases + ag_w3

  int tid = threadIdx.x, lane = tid & 63, wv = tid >> 6;
  int g = lane >> 5, c31 = lane & 31;

  sb[tid] = b1[tid];
  sb[256 + tid] = b2[tid];
  if (tid < 128) {
    sb[512 + tid] = b3[tid];
    sb[640 + tid] = ab1[tid];
    sb[768 + tid] = ab2[tid];
    sb[896 + tid] = ag3[tid];
  }
  if (tid == 0) sb[1024] = ab3[0];

  int e = blockIdx.x * 128 + wv * 32 + c31;
  bool ev = (e < E);
  int ec = ev ? e : (E - 1);
  int se = senders[ec], re = receivers[ec];
  const h16* pe = edges_h + (size_t)ec * 16;
  const h16* ps = nodes_h + (size_t)se * 128;
  const h16* pr = nodes_h + (size_t)re * 128;

  stage_tile<8>(wbuf[0], w1t, 288, 0, tid);

  // feats^T B-frag: segment chosen by (uniform, compile-time) ks
  auto loadB1 = [&](int ks) -> half8 {
    if (ks >= 17) { half8 z = {}; return z; }  // K pad 272..287
    const h16* base = (ks == 0) ? pe : (ks < 9) ? (ps + 16 * ks - 16) : (pr + 16 * ks - 144);
    return *(const half8*)(base + 8 * g);
  };

  // ---- GEMM1: h1^T[256][32e] = W1^T @ feats^T, K=288 (9 tiles, global 0..8)
  f32x16 acc1[8];
#pragma unroll
  for (int i = 0; i < 8; ++i) acc1[i] = f32x16{};
  half8 bq0 = loadB1(0), bq1 = loadB1(1);
#pragma unroll
  for (int kt = 0; kt < 9; ++kt) {
    __syncthreads();
    if (kt < 8) stage_tile<8>(wbuf[(kt + 1) & 1], w1t, 288, kt + 1, tid);
    else        stage_tile<8>(wbuf[1], w2t, 256, 0, tid);
    half8 n0 = {}, n1 = {};
    if (kt < 8) { n0 = loadB1(2 * kt + 2); n1 = loadB1(2 * kt + 3); }
    const h16* rb = wbuf[kt & 1];
#pragma unroll
    for (int mf = 0; mf < 8; ++mf) acc1[mf] = MFMA(ldsA(rb, mf, 0, lane), bq0, acc1[mf]);
#pragma unroll
    for (int mf = 0; mf < 8; ++mf) acc1[mf] = MFMA(ldsA(rb, mf, 1, lane), bq1, acc1[mf]);
    bq0 = n0; bq1 = n1;
  }
  unsigned hreg1[8][8];
#pragma unroll
  for (int mf = 0; mf < 8; ++mf) pack_frag<true>(hreg1[mf], acc1[mf], sb + 32 * mf, g);

  // ---- GEMM2: h2^T = W2^T @ h1^T, K=256 (tiles 9..16)
  f32x16 acc2[8];
#pragma unroll
  for (int i = 0; i < 8; ++i) acc2[i] = f32x16{};
  gemm_hregB<8, 8, 9, 4>(acc2, hreg1, w2t, 256, w3t, 256, wbuf, tid, lane);
  unsigned hreg2[8][8];
#pragma unroll
  for (int mf = 0; mf < 8; ++mf) pack_frag<false>(hreg2[mf], acc2[mf], sb + 256 + 32 * mf, g);

  // ---- GEMM3: msgs^T[128][32e] = W3^T @ h2^T, K=256 (tiles 17..24)
  f32x16 acc3[4];
#pragma unroll
  for (int i = 0; i < 4; ++i) acc3[i] = f32x16{};
  gemm_hregB<4, 8, 17, 4>(acc3, hreg2, w3t, 256, a1t, 128, wbuf, tid, lane);
  unsigned hreg3[4][8];
  unsigned* mrow = (unsigned*)(msgs_h + (size_t)ec * 128);
#pragma unroll
  for (int mf = 0; mf < 4; ++mf) {
    pack_frag<false>(hreg3[mf], acc3[mf], sb + 512 + 32 * mf, g);
    if (ev) {
#pragma unroll
      for (int j = 0; j < 8; ++j)
        mrow[16 * mf + (j & 1) + 4 * (j >> 1) + 2 * g] = hreg3[mf][j];
    }
  }

  // ---- GEMM4: g1^T = Ag1^T @ msgs^T, K=128 (tiles 25..28)
  f32x16 acc4[4];
#pragma unroll
  for (int i = 0; i < 4; ++i) acc4[i] = f32x16{};
  gemm_hregB<4, 4, 25, 4>(acc4, hreg3, a1t, 128, a2t, 128, wbuf, tid, lane);
  unsigned hreg4[4][8];
#pragma unroll
  for (int mf = 0; mf < 4; ++mf) pack_frag<true>(hreg4[mf], acc4[mf], sb + 640 + 32 * mf, g);

  // ---- GEMM5: g2^T = Ag2^T @ g1^T, K=128 (tiles 29..32)
  f32x16 acc5[4];
#pragma unroll
  for (int i = 0; i < 4; ++i) acc5[i] = f32x16{};
  gemm_hregB<4, 4, 29, 4>(acc5, hreg4, a2t, 128, (const h16*)nullptr, 0, wbuf, tid, lane);

  // ---- gate[e] = (g2 + ab2) . ag_w3 + ab3
  float gs = 0.f;
#pragma unroll
  for (int mf = 0; mf < 4; ++mf)
#pragma unroll
    for (int r = 0; r < 16; ++r) {
      int m = 32 * mf + (r & 3) + 8 * (r >> 2) + 4 * g;
      gs += (acc5[mf][r] + sb[768 + m]) * sb[896 + m];
    }
  unsigned xa = __float_as_uint(gs), xb = xa;
  lane_swap(xa, xb);  // xa = lo-half gs for all, xb = hi-half gs for all
  float tot = __uint_as_float(xa) + __uint_as_float(xb) + sb[1024];
  if (lane < 32 && ev) {
    gate[e] = tot;
    atomicMax(segmax + re, ordf(tot));
  }
}

// ---------------------------------------------------------------------------
// Update kernel: [nodes | aggr](256) -> update MLP -> out(128) fp32
// ---------------------------------------------------------------------------
__global__ __launch_bounds__(256, 2) void k_update(
    const h16* __restrict__ nodes_h, const h16* __restrict__ aggr_h,
    const h16* __restrict__ u1t, const h16* __restrict__ u2t, const h16* __restrict__ u3t,
    const float* __restrict__ b1, const float* __restrict__ b2, const float* __restrict__ b3,
    float* __restrict__ out, int N)
{
  __shared__ h16 wbuf[2][8192];
  __shared__ float sb[640];
  int tid = threadIdx.x, lane = tid & 63, wv = tid >> 6;
  int g = lane >> 5, c31 = lane & 31;
  sb[tid] = b1[tid];
  sb[256 + tid] = b2[tid];
  if (tid < 128) sb[512 + tid] = b3[tid];

  int n = blockIdx.x * 128 + wv * 32 + c31;
  int nc = (n < N) ? n : (N - 1);
  const h16* pn = nodes_h + (size_t)nc * 128;
  const h16* pa = aggr_h + (size_t)nc * 128;
  auto loadB = [&](int ks) -> half8 {
    const h16* base = (ks < 8) ? (pn + 16 * ks) : (pa + 16 * ks - 128);
    return *(const half8*)(base + 8 * g);
  };

  stage_tile<8>(wbuf[0], u1t, 256, 0, tid);
  f32x16 acc1[8];
#pragma unroll
  for (int i = 0; i < 8; ++i) acc1[i] = f32x16{};
  half8 bq0 = loadB(0), bq1 = loadB(1);
#pragma unroll
  for (int kt = 0; kt < 8; ++kt) {
    __syncthreads();
    if (kt < 7) stage_tile<8>(wbuf[(kt + 1) & 1], u1t, 256, kt + 1, tid);
    else        stage_tile<8>(wbuf[0], u2t, 256, 0, tid);
    half8 n0 = {}, n1 = {};
    if (kt < 7) { n0 = loadB(2 * kt + 2); n1 = loadB(2 * kt + 3); }
    const h16* rb = wbuf[kt & 1];
#pragma unroll
    for (int mf = 0; mf < 8; ++mf) acc1[mf] = MFMA(ldsA(rb, mf, 0, lane), bq0, acc1[mf]);
#pragma unroll
    for (int mf = 0; mf < 8; ++mf) acc1[mf] = MFMA(ldsA(rb, mf, 1, lane), bq1, acc1[mf]);
    bq0 = n0; bq1 = n1;
  }
  unsigned hr1[8][8];
#pragma unroll
  for (int mf = 0; mf < 8; ++mf) pack_frag<true>(hr1[mf], acc1[mf], sb + 32 * mf, g);

  f32x16 acc2[8];
#pragma unroll
  for (int i = 0; i < 8; ++i) acc2[i] = f32x16{};
  gemm_hregB<8, 8, 8, 4>(acc2, hr1, u2t, 256, u3t, 256, wbuf, tid, lane);
  unsigned hr2[8][8];
#pragma unroll
  for (int mf = 0; mf < 8; ++mf) pack_frag<false>(hr2[mf], acc2[mf], sb + 256 + 32 * mf, g);

  f32x16 acc3[4];
#pragma unroll
  for (int i = 0; i < 4; ++i) acc3[i] = f32x16{};
  gemm_hregB<4, 8, 16, 4>(acc3, hr2, u3t, 256, (const h16*)nullptr, 0, wbuf, tid, lane);

  if (n < N) {
    float2* orow = (float2*)(out + (size_t)n * 128);
#pragma unroll
    for (int mf = 0; mf < 4; ++mf)
#pragma unroll
      for (int j = 0; j < 8; ++j) {
        int m = 32 * mf + 2 * (j & 1) + 8 * (j >> 1) + 4 * g;
        float2 v;
        v.x = acc3[mf][2 * j]     + sb[512 + m];
        v.y = acc3[mf][2 * j + 1] + sb[512 + m + 1];
        orow[m >> 1] = v;
      }
  }
}

// ---------------------------------------------------------------------------
// Softmax denom (round-1-proven)
// ---------------------------------------------------------------------------
__global__ void k_denom(const float* __restrict__ gate, const int* __restrict__ recv,
                        const unsigned* __restrict__ segmax, float* __restrict__ denom, int E) {
  int t = blockIdx.x * 256 + threadIdx.x;
  if (t >= E) return;
  int r = recv[t];
  float w = __expf(gate[t] - ordinv(segmax[r]));
  atomicAdd(denom + r, w);
}

// ---------------------------------------------------------------------------
// CSR build: histogram -> single-wave exclusive scan -> fill
// ---------------------------------------------------------------------------
__global__ void k_hist(const int* __restrict__ recv, int* __restrict__ count, int E) {
  int e = blockIdx.x * 256 + threadIdx.x;
  if (e >= E) return;
  atomicAdd(count + recv[e], 1);
}

// One wave: lane owns a contiguous chunk of ceil(N/64) counts.
__global__ __launch_bounds__(64) void k_scan(const int* __restrict__ count,
                                             int* __restrict__ starts,
                                             int* __restrict__ cursor, int N) {
  int lane = threadIdx.x;
  int chunk = (N + 63) >> 6;
  int lo = lane * chunk;
  int hi = lo + chunk;
  if (lo > N) lo = N;
  if (hi > N) hi = N;
  int sum = 0;
  for (int i = lo; i < hi; ++i) sum += count[i];
  int x = sum;
#pragma unroll
  for (int off = 1; off < 64; off <<= 1) {
    int t = __shfl_up(x, off, 64);
    if (lane >= off) x += t;
  }
  int run = x - sum;  // exclusive prefix of this lane's chunk
  for (int i = lo; i < hi; ++i) {
    starts[i] = run;
    cursor[i] = run;
    run += count[i];
  }
}

__global__ void k_fill(const int* __restrict__ recv, int* __restrict__ cursor,
                       int* __restrict__ elist, int E) {
  int e = blockIdx.x * 256 + threadIdx.x;
  if (e >= E) return;
  int pos = atomicAdd(cursor + recv[e], 1);
  elist[pos] = e;
}

// ---------------------------------------------------------------------------
// Gather aggregation: one wave per node, weighted sum of msgs over CSR edges.
// Softmax stats (segmax, denom) come from the proven atomic path.
// ---------------------------------------------------------------------------
__global__ __launch_bounds__(256) void k_gather(
    const float* __restrict__ gate, const unsigned* __restrict__ segmax,
    const float* __restrict__ denom, const int* __restrict__ starts,
    const int* __restrict__ count, const int* __restrict__ elist,
    const h16* __restrict__ msgs_h, h16* __restrict__ aggr_h, int N)
{
  int node = (blockIdx.x * 256 + threadIdx.x) >> 6;
  int lane = threadIdx.x & 63;
  if (node >= N) return;
  int s = starts[node], c = count[node];
  float m = ordinv(segmax[node]);
  float inv = (c > 0) ? 1.f / denom[node] : 0.f;

  float ax = 0.f, ay = 0.f;
  for (int i = 0; i < c; ++i) {
    int e = elist[s + i];
    float w = __expf(gate[e] - m);
    unsigned mv = ((const unsigned*)msgs_h)[(size_t)e * 64 + lane];
    h16x2 hh = __builtin_bit_cast(h16x2, mv);
    ax += w * (float)hh[0];
    ay += w * (float)hh[1];
  }
  union { h16 h[2]; unsigned u; } o;   // RNE converts (match round-1 numerics)
  o.h[0] = (h16)(ax * inv);
  o.h[1] = (h16)(ay * inv);
  ((unsigned*)aggr_h)[(size_t)node * 64 + lane] = o.u;
}

// ---------------------------------------------------------------------------
// Converts
// ---------------------------------------------------------------------------
__global__ void k_f2h(const float* __restrict__ s, h16* __restrict__ d, long n4) {
  long i = (long)blockIdx.x * 256 + threadIdx.x;
  if (i >= n4) return;
  float4 v = ((const float4*)s)[i];
  union { h16 h[4]; uint2 u; } o;
  o.h[0] = (h16)v.x; o.h[1] = (h16)v.y; o.h[2] = (h16)v.z; o.h[3] = (h16)v.w;
  ((uint2*)d)[i] = o.u;
}

// wt[o][k] = w[k][o] (f16), zero-padded to Kp
__global__ void k_wt(const float* __restrict__ w, h16* __restrict__ wt, int K, int O, int Kp) {
  int t = blockIdx.x * 256 + threadIdx.x;
  if (t >= O * Kp) return;
  int o = t / Kp, k = t - o * Kp;
  wt[t] = (k < K) ? (h16)w[(size_t)k * O + o] : (h16)0.f;
}

// ---------------------------------------------------------------------------
extern "C" void kernel_launch(void* const* d_in, const int* in_sizes, int n_in,
                              void* d_out, int out_size, void* d_ws, size_t ws_size,
                              hipStream_t stream) {
  const float* nodes  = (const float*)d_in[0];
  const float* edges  = (const float*)d_in[1];
  const int* senders  = (const int*)d_in[2];
  const int* receivers= (const int*)d_in[3];
  const float* msg_w1 = (const float*)d_in[4];  const float* msg_b1 = (const float*)d_in[5];
  const float* msg_w2 = (const float*)d_in[6];  const float* msg_b2 = (const float*)d_in[7];
  const float* msg_w3 = (const float*)d_in[8];  const float* msg_b3 = (const float*)d_in[9];
  const float* ag_w1  = (const float*)d_in[10]; const float* ag_b1  = (const float*)d_in[11];
  const float* ag_w2  = (const float*)d_in[12]; const float* ag_b2  = (const float*)d_in[13];
  const float* ag_w3  = (const float*)d_in[14]; const float* ag_b3  = (const float*)d_in[15];
  const float* up_w1  = (const float*)d_in[16]; const float* up_b1  = (const float*)d_in[17];
  const float* up_w2  = (const float*)d_in[18]; const float* up_b2  = (const float*)d_in[19];
  const float* up_w3  = (const float*)d_in[20]; const float* up_b3  = (const float*)d_in[21];

  int N = in_sizes[0] / 128;
  int E = in_sizes[2];
  float* out = (float*)d_out;

  char* ws = (char*)d_ws;
  size_t off = 0;
  auto alloc = [&](size_t bytes) -> char* {
    char* p = ws + off; off += (bytes + 255) & ~(size_t)255; return p;
  };
  h16* nodes_h = (h16*)alloc((size_t)N * 128 * 2);
  h16* edges_h = (h16*)alloc((size_t)E * 16 * 2);
  h16* w1t = (h16*)alloc(256 * 288 * 2);
  h16* w2t = (h16*)alloc(256 * 256 * 2);
  h16* w3t = (h16*)alloc(128 * 256 * 2);
  h16* a1t = (h16*)alloc(128 * 128 * 2);
  h16* a2t = (h16*)alloc(128 * 128 * 2);
  h16* u1t = (h16*)alloc(256 * 256 * 2);
  h16* u2t = (h16*)alloc(256 * 256 * 2);
  h16* u3t = (h16*)alloc(128 * 256 * 2);
  h16* msgs_h = (h16*)alloc((size_t)E * 128 * 2);
  float* gate = (float*)alloc((size_t)E * 4);
  unsigned* segmax = (unsigned*)alloc((size_t)N * 4);
  float* denom = (float*)alloc((size_t)N * 4);
  int* count  = (int*)alloc((size_t)N * 4);
  int* starts = (int*)alloc((size_t)N * 4);
  int* cursor = (int*)alloc((size_t)N * 4);
  int* elist  = (int*)alloc((size_t)E * 4);
  h16* aggr_h = (h16*)alloc((size_t)N * 128 * 2);

  hipMemsetAsync(segmax, 0, (size_t)N * 4, stream);
  hipMemsetAsync(denom, 0, (size_t)N * 4, stream);
  hipMemsetAsync(count, 0, (size_t)N * 4, stream);

  // converts
  long n4n = (long)N * 128 / 4, n4e = (long)E * 16 / 4;
  k_f2h<<<(n4n + 255) / 256, 256, 0, stream>>>(nodes, nodes_h, n4n);
  k_f2h<<<(n4e + 255) / 256, 256, 0, stream>>>(edges, edges_h, n4e);
  k_wt<<<(256 * 288 + 255) / 256, 256, 0, stream>>>(msg_w1, w1t, 272, 256, 288);
  k_wt<<<(256 * 256 + 255) / 256, 256, 0, stream>>>(msg_w2, w2t, 256, 256, 256);
  k_wt<<<(128 * 256 + 255) / 256, 256, 0, stream>>>(msg_w3, w3t, 256, 128, 256);
  k_wt<<<(128 * 128 + 255) / 256, 256, 0, stream>>>(ag_w1, a1t, 128, 128, 128);
  k_wt<<<(128 * 128 + 255) / 256, 256, 0, stream>>>(ag_w2, a2t, 128, 128, 128);
  k_wt<<<(256 * 256 + 255) / 256, 256, 0, stream>>>(up_w1, u1t, 256, 256, 256);
  k_wt<<<(256 * 256 + 255) / 256, 256, 0, stream>>>(up_w2, u2t, 256, 256, 256);
  k_wt<<<(128 * 256 + 255) / 256, 256, 0, stream>>>(up_w3, u3t, 256, 128, 256);

  // CSR build
  k_hist<<<(E + 255) / 256, 256, 0, stream>>>(receivers, count, E);
  k_scan<<<1, 64, 0, stream>>>(count, starts, cursor, N);
  k_fill<<<(E + 255) / 256, 256, 0, stream>>>(receivers, cursor, elist, E);

  // fused edge pipeline (msgs + gate + segmax)
  k_edge<<<(E + 127) / 128, 256, 0, stream>>>(
      nodes_h, edges_h, senders, receivers, w1t, w2t, w3t, a1t, a2t,
      msg_b1, msg_b2, msg_b3, ag_b1, ag_b2, ag_w3, ag_b3,
      msgs_h, gate, segmax, E);

  // softmax denom (proven atomic path) + gather aggregation
  k_denom<<<(E + 255) / 256, 256, 0, stream>>>(gate, receivers, segmax, denom, E);
  k_gather<<<((size_t)N * 64 + 255) / 256, 256, 0, stream>>>(
      gate, segmax, denom, starts, count, elist, msgs_h, aggr_h, N);

  // node update
  k_update<<<(N + 127) / 128, 256, 0, stream>>>(
      nodes_h, aggr_h, u1t, u2t, u3t, up_b1, up_b2, up_b3, out, N);
}